// Round 11
// baseline (2123.551 us; speedup 1.0000x reference)
//
#include <hip/hip_runtime.h>
#include <math.h>

#define NB 32
#define NT 512
#define ND 256
#define NH 4
#define NLAYER 6
#define TOUT 2048

typedef __attribute__((ext_vector_type(8))) short bf16x8;
typedef __attribute__((ext_vector_type(4))) float f32x4;
typedef __attribute__((ext_vector_type(16))) float f32x16;

static __device__ __forceinline__ unsigned short f2b(float f) {
    union { float f; unsigned int u; } x; x.f = f;
    unsigned int u = x.u;
    return (unsigned short)((u + 0x7FFFu + ((u >> 16) & 1u)) >> 16);
}
static __device__ __forceinline__ float b2f(unsigned short s) {
    union { unsigned int u; float f; } x; x.u = ((unsigned int)s) << 16;
    return x.f;
}

// swizzles: SW for 64B rows (4 blocks), SW8 for 128B rows (8 blocks)
#define SW(r)  (((r) >> 1) & 3)
#define SW8(r) ((r) & 7)

// ---------------- workspace layout (float offsets) ----------------
#define OFF_X    0ull
#define OFF_FFH  4194304ull
#define OFF_WBT  12582912ull
#define OFF_CWT  14942208ull
#define OFF_QKV  20971520ull
#define OFF_ATTN 33554432ull
#define OFF_PROJ 37748736ull
#define OFF_INT  41951232ull

// ---------------- embedding + positional encoding ----------------
__global__ __launch_bounds__(256) void embed_kernel(const int* __restrict__ text,
                                                    const float* __restrict__ emb,
                                                    float* __restrict__ x)
{
    const int row = blockIdx.x;
    const int d = threadIdx.x;
    const int t = row & (NT - 1);
    const int id = text[row];
    const int j2 = (d >> 1) * 2;
    const float c = -9.210340371976184f / 256.0f;
    float freq = expf((float)j2 * c);
    float ang = (float)t * freq;
    float pe = (d & 1) ? cosf(ang) : sinf(ang);
    x[(size_t)row * ND + d] = emb[(size_t)id * ND + d] + pe;
}

// ---------------- merged transformer weight transpose: fp32 [K,N] -> bf16 [N,K] ----------------
__global__ __launch_bounds__(256) void wqall_kernel(const float* __restrict__ Wqkv,
                                                    const float* __restrict__ Wo,
                                                    const float* __restrict__ W1,
                                                    const float* __restrict__ W2,
                                                    unsigned short* __restrict__ Wbt)
{
    __shared__ float tile[32][33];
    const int tt = blockIdx.x, layer = blockIdx.y;
    const float* src; int K, N, n0, k0, inLS; size_t outSeg;
    if (tt < 192)      { src = Wqkv; K = 256;  N = 768;  n0 = (tt % 24) * 32; k0 = (tt / 24) * 32; inLS = 196608; outSeg = 0; }
    else if (tt < 256) { int t2 = tt - 192; src = Wo; K = 256; N = 256;  n0 = (t2 & 7) * 32;  k0 = (t2 >> 3) * 32; inLS = 65536;  outSeg = 196608; }
    else if (tt < 512) { int t3 = tt - 256; src = W1; K = 256; N = 1024; n0 = (t3 & 31) * 32; k0 = (t3 >> 5) * 32; inLS = 262144; outSeg = 262144; }
    else               { int t4 = tt - 512; src = W2; K = 1024; N = 256; n0 = (t4 & 7) * 32;  k0 = (t4 >> 3) * 32; inLS = 262144; outSeg = 524288; }
    const float* Wl = src + (size_t)layer * inLS;
    unsigned short* ol = Wbt + (size_t)layer * 786432 + outSeg;
    const int tx = threadIdx.x & 31, ty = threadIdx.x >> 5;
#pragma unroll
    for (int j = 0; j < 4; ++j)
        tile[ty + j * 8][tx] = Wl[(size_t)(k0 + ty + j * 8) * N + n0 + tx];
    __syncthreads();
#pragma unroll
    for (int j = 0; j < 4; ++j)
        ol[(size_t)(n0 + ty + j * 8) * K + k0 + tx] = f2b(tile[tx][ty + j * 8]);
}

// ---------------- merged conv weight transpose ----------------
__global__ __launch_bounds__(256) void wtransball_kernel(const float* __restrict__ dp_w1,
                                                         const float* __restrict__ dp_w2,
                                                         const float* __restrict__ dec_w1,
                                                         const float* __restrict__ dec_w2,
                                                         unsigned short* __restrict__ cw)
{
    int gid = blockIdx.x * 256 + threadIdx.x;
    if (gid >= 884736) return;
    const float* src; int CIN = 256, COUT, KS, idx;
    if (gid < 196608)      { src = dp_w1;  COUT = 256; KS = 3; idx = gid; }
    else if (gid < 393216) { src = dp_w2;  COUT = 256; KS = 3; idx = gid - 196608; }
    else if (gid < 720896) { src = dec_w1; COUT = 256; KS = 5; idx = gid - 393216; }
    else                   { src = dec_w2; COUT = 128; KS = 5; idx = gid - 720896; }
    int c = idx % CIN;
    int r = idx / CIN;
    int o = r % COUT;
    int k = r / COUT;
    cw[gid] = f2b(src[(o * CIN + c) * KS + k]);
}

// ---------------- bf16 MFMA GEMM (qkv / ff1): BK=64, reg-prefetch dbuf ----------------
template<int NTILE, bool RELU, bool ABF16, bool CBF16, bool VOUT>
__global__ __launch_bounds__(256) void gemmbf_kernel(const void* __restrict__ A_,
                                                     const unsigned short* __restrict__ Bt,
                                                     const float* __restrict__ bias,
                                                     void* __restrict__ C_,
                                                     unsigned short* __restrict__ vt,
                                                     int M, int N, int K)
{
    constexpr int MT = (NTILE == 128) ? 2 : 1;
    constexpr int BUNITS = NTILE / 32;     // B stage units per thread
    __shared__ __align__(16) unsigned short Asb[128 * 64];
    __shared__ __align__(16) unsigned short Bsb[NTILE * 64];
    const int tid = threadIdx.x;
    const int lane = tid & 63, wave = tid >> 6;
    const int ln = lane & 31, hi = lane >> 5;
    const int row0 = blockIdx.y * 128, col0 = blockIdx.x * NTILE;
    const int mOff = (NTILE == 128) ? (wave >> 1) * 64 : wave * 32;
    const int nOff = (NTILE == 128) ? (wave & 1) * 64 : 0;
    const float* Af = (const float*)A_;
    const unsigned short* Ab = (const unsigned short*)A_;
    float* Cf = (float*)C_;
    unsigned short* Cb = (unsigned short*)C_;
    f32x16 acc[MT][2] = {};
    uint4 aR[4], bR[BUNITS];

    auto loadA = [&](int k0) {
#pragma unroll
        for (int it = 0; it < 4; ++it) {
            int u = it * 256 + tid;
            int m = u >> 3, blk = u & 7;
            if (ABF16) {
                aR[it] = *(const uint4*)&Ab[(size_t)(row0 + m) * K + k0 + blk * 8];
            } else {
                float4 v0 = *(const float4*)&Af[(size_t)(row0 + m) * K + k0 + blk * 8];
                float4 v1 = *(const float4*)&Af[(size_t)(row0 + m) * K + k0 + blk * 8 + 4];
                unsigned short s8[8];
                s8[0] = f2b(v0.x); s8[1] = f2b(v0.y); s8[2] = f2b(v0.z); s8[3] = f2b(v0.w);
                s8[4] = f2b(v1.x); s8[5] = f2b(v1.y); s8[6] = f2b(v1.z); s8[7] = f2b(v1.w);
                aR[it] = *(uint4*)s8;
            }
        }
    };
    auto loadB = [&](int k0) {
#pragma unroll
        for (int it = 0; it < BUNITS; ++it) {
            int u = it * 256 + tid;
            int n = u >> 3, blk = u & 7;
            bR[it] = *(const uint4*)&Bt[(size_t)(col0 + n) * K + k0 + blk * 8];
        }
    };
    auto storeAB = [&]() {
#pragma unroll
        for (int it = 0; it < 4; ++it) {
            int u = it * 256 + tid;
            int m = u >> 3, blk = u & 7;
            *(uint4*)&Asb[m * 64 + ((blk ^ SW8(m)) << 3)] = aR[it];
        }
#pragma unroll
        for (int it = 0; it < BUNITS; ++it) {
            int u = it * 256 + tid;
            int n = u >> 3, blk = u & 7;
            *(uint4*)&Bsb[n * 64 + ((blk ^ SW8(n)) << 3)] = bR[it];
        }
    };

    loadA(0); loadB(0); storeAB();
    const int nc = K >> 6;
    for (int c = 0; c < nc; ++c) {
        __syncthreads();
        if (c + 1 < nc) { loadA((c + 1) << 6); loadB((c + 1) << 6); }
#pragma unroll
        for (int kh = 0; kh < 4; ++kh) {
            const int kb = kh * 2 + hi;
            bf16x8 af[MT], bfr[2];
#pragma unroll
            for (int mt = 0; mt < MT; ++mt) {
                int r = mOff + mt * 32 + ln;
                af[mt] = *(const bf16x8*)&Asb[r * 64 + ((kb ^ SW8(r)) << 3)];
            }
#pragma unroll
            for (int nt = 0; nt < 2; ++nt) {
                int r = nOff + nt * 32 + ln;
                bfr[nt] = *(const bf16x8*)&Bsb[r * 64 + ((kb ^ SW8(r)) << 3)];
            }
#pragma unroll
            for (int mt = 0; mt < MT; ++mt)
#pragma unroll
                for (int nt = 0; nt < 2; ++nt)
                    acc[mt][nt] = __builtin_amdgcn_mfma_f32_32x32x16_bf16(
                        af[mt], bfr[nt], acc[mt][nt], 0, 0, 0);
        }
        __syncthreads();
        if (c + 1 < nc) storeAB();
    }
#pragma unroll
    for (int mt = 0; mt < MT; ++mt)
#pragma unroll
        for (int nt = 0; nt < 2; ++nt) {
            int col = col0 + nOff + nt * 32 + ln;
            float bi = bias[col];
#pragma unroll
            for (int g = 0; g < 4; ++g) {
                unsigned short s4[4];
#pragma unroll
                for (int r4 = 0; r4 < 4; ++r4) {
                    int row = row0 + mOff + mt * 32 + hi * 4 + g * 8 + r4;
                    float v = acc[mt][nt][g * 4 + r4] + bi;
                    if (RELU) v = fmaxf(v, 0.f);
                    if (CBF16) { s4[r4] = f2b(v); Cb[(size_t)row * N + col] = s4[r4]; }
                    else       Cf[(size_t)row * N + col] = v;
                }
                if (VOUT && col >= 512) {
                    int rowg = row0 + mOff + mt * 32 + hi * 4 + g * 8;
                    int b = rowg >> 9, t = rowg & (NT - 1);
                    int hh = (col - 512) >> 6, dd = (col - 512) & 63;
                    *(uint2*)&vt[((size_t)(b * NH + hh) * 64 + dd) * NT + t] = *(uint2*)s4;
                }
            }
        }
}

// ---------------- bf16 MFMA GEMM + residual + LayerNorm (proj / ff2): BK=64, prefetch ----------------
__global__ __launch_bounds__(256) void gemmln_kernel(const unsigned short* __restrict__ A,
                                                     const unsigned short* __restrict__ Bt,
                                                     const float* __restrict__ bias,
                                                     const float* __restrict__ lng,
                                                     const float* __restrict__ lnb,
                                                     float* __restrict__ x,
                                                     int K)
{
    __shared__ __align__(16) unsigned short Asb[64 * 64];
    __shared__ __align__(16) unsigned short Bsb[256 * 64];
    __shared__ float sred[64][2][2];
    const int tid = threadIdx.x;
    const int lane = tid & 63, wave = tid >> 6;
    const int ln = lane & 31, hi = lane >> 5;
    const int row0 = blockIdx.x * 64;
    const int mOff = (wave >> 1) * 32;
    const int colbase = (wave & 1) * 128;
    f32x16 acc[4] = {};
    uint4 aR[2], bR[8];

    auto loadA = [&](int k0) {
#pragma unroll
        for (int it = 0; it < 2; ++it) {
            int u = it * 256 + tid;
            int m = u >> 3, blk = u & 7;
            aR[it] = *(const uint4*)&A[(size_t)(row0 + m) * K + k0 + blk * 8];
        }
    };
    auto loadB = [&](int k0) {
#pragma unroll
        for (int it = 0; it < 8; ++it) {
            int u = it * 256 + tid;
            int n = u >> 3, blk = u & 7;
            bR[it] = *(const uint4*)&Bt[(size_t)n * K + k0 + blk * 8];
        }
    };
    auto storeAB = [&]() {
#pragma unroll
        for (int it = 0; it < 2; ++it) {
            int u = it * 256 + tid;
            int m = u >> 3, blk = u & 7;
            *(uint4*)&Asb[m * 64 + ((blk ^ SW8(m)) << 3)] = aR[it];
        }
#pragma unroll
        for (int it = 0; it < 8; ++it) {
            int u = it * 256 + tid;
            int n = u >> 3, blk = u & 7;
            *(uint4*)&Bsb[n * 64 + ((blk ^ SW8(n)) << 3)] = bR[it];
        }
    };

    loadA(0); loadB(0); storeAB();
    const int nc = K >> 6;
    for (int c = 0; c < nc; ++c) {
        __syncthreads();
        if (c + 1 < nc) { loadA((c + 1) << 6); loadB((c + 1) << 6); }
#pragma unroll
        for (int kh = 0; kh < 4; ++kh) {
            const int kb = kh * 2 + hi;
            int r = mOff + ln;
            bf16x8 af = *(const bf16x8*)&Asb[r * 64 + ((kb ^ SW8(r)) << 3)];
#pragma unroll
            for (int nt = 0; nt < 4; ++nt) {
                int rb = colbase + nt * 32 + ln;
                bf16x8 bfr = *(const bf16x8*)&Bsb[rb * 64 + ((kb ^ SW8(rb)) << 3)];
                acc[nt] = __builtin_amdgcn_mfma_f32_32x32x16_bf16(af, bfr, acc[nt], 0, 0, 0);
            }
        }
        __syncthreads();
        if (c + 1 < nc) storeAB();
    }

    float bi[4], gv[4], bv[4];
#pragma unroll
    for (int nt = 0; nt < 4; ++nt) {
        int col = colbase + nt * 32 + ln;
        bi[nt] = bias[col]; gv[nt] = lng[col]; bv[nt] = lnb[col];
    }
#pragma unroll
    for (int g = 0; g < 4; ++g)
#pragma unroll
        for (int r4 = 0; r4 < 4; ++r4) {
            int rl = mOff + hi * 4 + g * 8 + r4;
            size_t base = (size_t)(row0 + rl) * ND + colbase + ln;
#pragma unroll
            for (int nt = 0; nt < 4; ++nt)
                acc[nt][g * 4 + r4] += bi[nt] + x[base + nt * 32];
        }
#pragma unroll
    for (int g = 0; g < 4; ++g)
#pragma unroll
        for (int r4 = 0; r4 < 4; ++r4) {
            int i = g * 4 + r4;
            float ps = acc[0][i] + acc[1][i] + acc[2][i] + acc[3][i];
            float ps2 = acc[0][i] * acc[0][i] + acc[1][i] * acc[1][i]
                      + acc[2][i] * acc[2][i] + acc[3][i] * acc[3][i];
#pragma unroll
            for (int o = 1; o < 32; o <<= 1) {
                ps += __shfl_xor(ps, o);
                ps2 += __shfl_xor(ps2, o);
            }
            if (ln == 0) {
                int rl = mOff + hi * 4 + g * 8 + r4;
                sred[rl][wave & 1][0] = ps;
                sred[rl][wave & 1][1] = ps2;
            }
        }
    __syncthreads();
#pragma unroll
    for (int g = 0; g < 4; ++g)
#pragma unroll
        for (int r4 = 0; r4 < 4; ++r4) {
            int i = g * 4 + r4;
            int rl = mOff + hi * 4 + g * 8 + r4;
            float s = sred[rl][0][0] + sred[rl][1][0];
            float s2 = sred[rl][0][1] + sred[rl][1][1];
            float m = s * (1.0f / 256.0f);
            float var = fmaxf(s2 * (1.0f / 256.0f) - m * m, 0.0f);
            float rinv = 1.0f / sqrtf(var + 1e-5f);
            size_t base = (size_t)(row0 + rl) * ND + colbase + ln;
#pragma unroll
            for (int nt = 0; nt < 4; ++nt)
                x[base + nt * 32] = (acc[nt][i] - m) * rinv * gv[nt] + bv[nt];
        }
}

// ---------------- attention v3: bf16 MFMA flash, computes O^T ----------------
__global__ __launch_bounds__(256, 2) void attn3_kernel(const unsigned short* __restrict__ qkv,
                                                       const unsigned short* __restrict__ vt,
                                                       unsigned short* __restrict__ out)
{
    __shared__ __align__(16) unsigned short sP[4][32 * 64];
    const int tid = threadIdx.x;
    const int lane = tid & 63, wave = tid >> 6;
    const int ln = lane & 31, hi = lane >> 5;
    const int h = blockIdx.y, b = blockIdx.z;
    const int q0 = blockIdx.x * 128 + wave * 32;
    const size_t base = (size_t)b * NT * 768;
    const int qoff = h * 64;
    const unsigned short* vbh = vt + (size_t)(b * NH + h) * 64 * NT;

    bf16x8 qf[4];
#pragma unroll
    for (int s = 0; s < 4; ++s)
        qf[s] = *(const bf16x8*)&qkv[base + (size_t)(q0 + ln) * 768 + qoff + s * 16 + hi * 8];

    float mrow[16], lrow[16];
#pragma unroll
    for (int i = 0; i < 16; ++i) { mrow[i] = -1e30f; lrow[i] = 0.f; }
    f32x16 oacc[2] = {};
    const float sc = 0.18033688011112042f;
    const int i0 = (ln & 3) | (((ln >> 3) & 3) << 2);
    const bool own = (((ln >> 2) & 1) == hi);
    unsigned short* Pw = &sP[wave][0];

    for (int ch = 0; ch < 8; ++ch) {
        const int s0 = ch * 64;
        f32x16 sacc[2] = {};
#pragma unroll
        for (int ct = 0; ct < 2; ++ct)
#pragma unroll
            for (int s = 0; s < 4; ++s) {
                bf16x8 kf = *(const bf16x8*)&qkv[base + (size_t)(s0 + ct * 32 + ln) * 768
                                                 + 256 + qoff + s * 16 + hi * 8];
                sacc[ct] = __builtin_amdgcn_mfma_f32_32x32x16_bf16(qf[s], kf, sacc[ct], 0, 0, 0);
            }
        float alpha[16];
#pragma unroll
        for (int i = 0; i < 16; ++i) {
            float s20 = sacc[0][i] * sc, s21 = sacc[1][i] * sc;
            float mx = fmaxf(s20, s21);
#pragma unroll
            for (int o = 1; o < 32; o <<= 1) mx = fmaxf(mx, __shfl_xor(mx, o));
            float mn = fmaxf(mrow[i], mx);
            alpha[i] = exp2f(mrow[i] - mn);
            mrow[i] = mn;
            float p0 = exp2f(s20 - mn);
            float p1 = exp2f(s21 - mn);
            sacc[0][i] = p0; sacc[1][i] = p1;
            float rs = p0 + p1;
#pragma unroll
            for (int o = 1; o < 32; o <<= 1) rs += __shfl_xor(rs, o);
            lrow[i] = lrow[i] * alpha[i] + rs;
        }
#pragma unroll
        for (int ct = 0; ct < 2; ++ct) {
            int kb = ct * 4 + (ln >> 3), k7 = ln & 7;
#pragma unroll
            for (int i = 0; i < 16; ++i) {
                int q = (i & 3) + 8 * (i >> 2) + 4 * hi;
                Pw[q * 64 + (((kb ^ (q & 7)) << 3) | k7)] = f2b(sacc[ct][i]);
            }
        }
        __syncthreads();
        {
            float av = alpha[i0];
            float ao = __shfl_xor(av, 32);
            float aq = own ? av : ao;
#pragma unroll
            for (int ct = 0; ct < 2; ++ct)
#pragma unroll
                for (int i = 0; i < 16; ++i)
                    oacc[ct][i] *= aq;
        }
#pragma unroll
        for (int s = 0; s < 4; ++s) {
            bf16x8 pf = *(const bf16x8*)&Pw[ln * 64 + (((s * 2 + hi) ^ (ln & 7)) << 3)];
#pragma unroll
            for (int ct = 0; ct < 2; ++ct) {
                bf16x8 vf = *(const bf16x8*)&vbh[(size_t)(ct * 32 + ln) * NT + s0 + s * 16 + hi * 8];
                oacc[ct] = __builtin_amdgcn_mfma_f32_32x32x16_bf16(vf, pf, oacc[ct], 0, 0, 0);
            }
        }
        __syncthreads();
    }
    float lv = lrow[i0];
    float lo = __shfl_xor(lv, 32);
    float linv = 1.0f / (own ? lv : lo);
    const int q = q0 + ln;
#pragma unroll
    for (int ct = 0; ct < 2; ++ct)
#pragma unroll
        for (int i = 0; i < 16; ++i) {
            int d = ct * 32 + (i & 3) + 8 * (i >> 2) + 4 * hi;
            out[(size_t)(b * NT + q) * ND + qoff + d] = f2b(oacc[ct][i] * linv);
        }
}

// ---------------- fused emotion MLP + add ----------------
__global__ __launch_bounds__(256) void fuse_kernel(const float* __restrict__ emo,
                                                   const float* __restrict__ We1,
                                                   const float* __restrict__ be1,
                                                   const float* __restrict__ We2,
                                                   const float* __restrict__ be2,
                                                   float* __restrict__ x)
{
    const int row = blockIdx.x;
    const int d = threadIdx.x;
    const float em = emo[row >> 9];
    float acc = be2[d];
    for (int j = 0; j < 64; ++j) {
        float h = fmaxf(em * We1[j] + be1[j], 0.0f);
        acc = fmaf(h, We2[j * ND + d], acc);
    }
    x[(size_t)row * ND + d] += acc;
}

// ---------------- unified bf16 MFMA conv: tile 256t x 64o, reg-prefetch dbuf ----------------
template<int CIN, int KS, bool IN_BF16, bool OUT_BF16, bool BN>
__global__ __launch_bounds__(256) void convk_kernel(const void* __restrict__ in_,
                                                    const unsigned short* __restrict__ wtb,
                                                    const float* __restrict__ bias,
                                                    const float* __restrict__ bng,
                                                    const float* __restrict__ bnb,
                                                    const float* __restrict__ bnm,
                                                    const float* __restrict__ bnv,
                                                    void* __restrict__ out_,
                                                    int T, int COUT)
{
    constexpr int PAD = (KS - 1) / 2;
    constexpr int TEXT = 256 + KS - 1;
    constexpr int AUNITS = (TEXT * 4 + 255) / 256;   // 5
    __shared__ __align__(16) unsigned short Asb[TEXT * 32];
    __shared__ __align__(16) unsigned short Bsb[KS * 64 * 32];
    const int tid = threadIdx.x;
    const int lane = tid & 63, wave = tid >> 6;
    const int ln = lane & 31, hi = lane >> 5;
    const int b = blockIdx.z;
    const int t0 = blockIdx.x * 256;
    const int o0 = blockIdx.y * 64;
    const int mOff = wave * 64;
    const float* inf = (const float*)in_;
    const unsigned short* inb = (const unsigned short*)in_;
    float* outf = (float*)out_;
    unsigned short* outb = (unsigned short*)out_;
    f32x16 acc[2][2] = {};
    uint4 aR[AUNITS], bR[KS];

    auto loadA = [&](int cc) {
#pragma unroll
        for (int it = 0; it < AUNITS; ++it) {
            int u = it * 256 + tid;
            if (u >= TEXT * 4) continue;
            int t = u >> 2, blk = u & 3;
            int tg = t0 - PAD + t;
            unsigned short s8[8] = {0, 0, 0, 0, 0, 0, 0, 0};
            if (tg >= 0 && tg < T) {
                if (IN_BF16) {
                    *(uint4*)s8 = *(const uint4*)&inb[((size_t)(b * T) + tg) * CIN + cc + blk * 8];
                } else {
                    float4 v0 = *(const float4*)&inf[((size_t)(b * T) + tg) * CIN + cc + blk * 8];
                    float4 v1 = *(const float4*)&inf[((size_t)(b * T) + tg) * CIN + cc + blk * 8 + 4];
                    s8[0] = f2b(v0.x); s8[1] = f2b(v0.y); s8[2] = f2b(v0.z); s8[3] = f2b(v0.w);
                    s8[4] = f2b(v1.x); s8[5] = f2b(v1.y); s8[6] = f2b(v1.z); s8[7] = f2b(v1.w);
                }
            }
            aR[it] = *(uint4*)s8;
        }
    };
    auto loadB = [&](int cc) {
#pragma unroll
        for (int it = 0; it < KS; ++it) {
            int u = it * 256 + tid;
            int row = u >> 2, blk = u & 3;
            int k = row >> 6, o = row & 63;
            bR[it] = *(const uint4*)&wtb[((size_t)k * COUT + o0 + o) * CIN + cc + blk * 8];
        }
    };
    auto storeAB = [&]() {
#pragma unroll
        for (int it = 0; it < AUNITS; ++it) {
            int u = it * 256 + tid;
            if (u >= TEXT * 4) continue;
            int t = u >> 2, blk = u & 3;
            *(uint4*)&Asb[t * 32 + ((blk ^ SW(t)) << 3)] = aR[it];
        }
#pragma unroll
        for (int it = 0; it < KS; ++it) {
            int u = it * 256 + tid;
            int row = u >> 2, blk = u & 3;
            *(uint4*)&Bsb[row * 32 + ((blk ^ SW(row)) << 3)] = bR[it];
        }
    };

    loadA(0); loadB(0); storeAB();
    for (int cc = 0; cc < CIN; cc += 32) {
        __syncthreads();
        if (cc + 32 < CIN) { loadA(cc + 32); loadB(cc + 32); }
#pragma unroll
        for (int kh = 0; kh < 2; ++kh) {
            const int kb = kh * 2 + hi;
#pragma unroll
            for (int tap = 0; tap < KS; ++tap) {
                bf16x8 af[2];
#pragma unroll
                for (int mt = 0; mt < 2; ++mt) {
                    int r = mOff + mt * 32 + ln + tap;
                    af[mt] = *(const bf16x8*)&Asb[r * 32 + ((kb ^ SW(r)) << 3)];
                }
#pragma unroll
                for (int nt = 0; nt < 2; ++nt) {
                    int rb = tap * 64 + nt * 32 + ln;
                    bf16x8 bfr = *(const bf16x8*)&Bsb[rb * 32 + ((kb ^ SW(rb)) << 3)];
#pragma unroll
                    for (int mt = 0; mt < 2; ++mt)
                        acc[mt][nt] = __builtin_amdgcn_mfma_f32_32x32x16_bf16(
                            af[mt], bfr, acc[mt][nt], 0, 0, 0);
                }
            }
        }
        __syncthreads();
        if (cc + 32 < CIN) storeAB();
    }
#pragma unroll
    for (int nt = 0; nt < 2; ++nt) {
        int col = o0 + nt * 32 + ln;
        float bi = bias[col];
        float scv = 1.f, shv = 0.f;
        if (BN) {
            scv = bng[col] / sqrtf(bnv[col] + 1e-5f);
            shv = bnb[col] - bnm[col] * scv;
        }
#pragma unroll
        for (int mt = 0; mt < 2; ++mt)
#pragma unroll
            for (int g = 0; g < 4; ++g)
#pragma unroll
                for (int r4 = 0; r4 < 4; ++r4) {
                    int row = t0 + mOff + mt * 32 + hi * 4 + g * 8 + r4;
                    float v = fmaxf(acc[mt][nt][g * 4 + r4] + bi, 0.f);
                    if (BN) v = v * scv + shv;
                    if (OUT_BF16) outb[((size_t)(b * T) + row) * COUT + col] = f2b(v);
                    else          outf[((size_t)(b * T) + row) * COUT + col] = v;
                }
    }
}

// ---------------- regulated-sequence materialization ----------------
__global__ __launch_bounds__(256) void reg_kernel(const float* __restrict__ x,
                                                  const int* __restrict__ tok,
                                                  unsigned short* __restrict__ reg)
{
    const int wave = threadIdx.x >> 6, lane = threadIdx.x & 63;
    const int row = blockIdx.x * 4 + wave;
    const int tk = tok[row];
    const int b = row >> 11;
    const int c4 = lane * 4;
    unsigned short s4[4] = {0, 0, 0, 0};
    if (tk >= 0) {
        float4 v = *(const float4*)&x[((size_t)(b * NT) + tk) * ND + c4];
        s4[0] = f2b(v.x); s4[1] = f2b(v.y); s4[2] = f2b(v.z); s4[3] = f2b(v.w);
    }
    *(uint2*)&reg[(size_t)row * ND + c4] = *(uint2*)s4;
}

// ---------------- duration: wave-per-row dot -> dur ----------------
__global__ __launch_bounds__(256) void dur_kernel(const float* __restrict__ h2,
                                                  const float* __restrict__ wo,
                                                  const float* __restrict__ bo,
                                                  int* __restrict__ dur)
{
    const int wave = threadIdx.x >> 6, lane = threadIdx.x & 63;
    const int row = blockIdx.x * 4 + wave;
    const int c4 = lane * 4;
    float4 h = *(const float4*)&h2[(size_t)row * ND + c4];
    float4 w4 = *(const float4*)&wo[c4];
    float s = h.x * w4.x + h.y * w4.y + h.z * w4.z + h.w * w4.w;
#pragma unroll
    for (int o = 1; o < 64; o <<= 1) s += __shfl_xor(s, o);
    if (lane == 0) {
        float d = rintf(expf(s + bo[0]));
        d = fminf(fmaxf(d, 1.0f), 8.0f);
        dur[row] = (int)d;
    }
}

// ---------------- fused scan + token map ----------------
__global__ __launch_bounds__(256) void scantok_kernel(const int* __restrict__ dur,
                                                      int* __restrict__ tok)
{
    __shared__ int st[NT];
    __shared__ int tot;
    const int b = blockIdx.x, tid = threadIdx.x;
    if (tid == 0) {
        int a = 0;
        for (int t = 0; t < NT; ++t) { st[t] = a; a += dur[b * NT + t]; }
        tot = a;
    }
    __syncthreads();
    for (int p = tid; p < TOUT; p += 256) {
        int res = -1;
        if (p < tot) {
            int lo = 0, hi = NT - 1;
            while (lo < hi) {
                int mid = (lo + hi + 1) >> 1;
                if (st[mid] <= p) lo = mid; else hi = mid - 1;
            }
            res = lo;
        }
        tok[b * TOUT + p] = res;
    }
}

// ---------------- decoder conv3: wave-per-output ----------------
__global__ __launch_bounds__(256) void conv3_kernel(const unsigned short* __restrict__ in,
                                                    const float* __restrict__ w,
                                                    const float* __restrict__ bias,
                                                    float* __restrict__ out)
{
    const int wave = threadIdx.x >> 6, lane = threadIdx.x & 63;
    const int gid = blockIdx.x * 4 + wave;
    const int b = gid >> 11, t = gid & (TOUT - 1);
    const int c = lane * 2;
    float w0[5], w1[5];
#pragma unroll
    for (int k = 0; k < 5; ++k) { w0[k] = w[c * 5 + k]; w1[k] = w[(c + 1) * 5 + k]; }
    float acc = 0.f;
#pragma unroll
    for (int k = 0; k < 5; ++k) {
        int t2 = t + k - 2;
        if (t2 < 0 || t2 >= TOUT) continue;
        unsigned int u = *(const unsigned int*)&in[((size_t)(b * TOUT) + t2) * 128 + c];
        acc = fmaf(b2f((unsigned short)(u & 0xFFFF)), w0[k], acc);
        acc = fmaf(b2f((unsigned short)(u >> 16)), w1[k], acc);
    }
#pragma unroll
    for (int o = 1; o < 64; o <<= 1) acc += __shfl_xor(acc, o);
    if (lane == 0) out[gid] = acc + bias[0];
}

// ---------------- orchestration ----------------
extern "C" void kernel_launch(void* const* d_in, const int* in_sizes, int n_in,
                              void* d_out, int out_size, void* d_ws, size_t ws_size,
                              hipStream_t stream)
{
    const int*   text    = (const int*)d_in[0];
    const float* emotion = (const float*)d_in[1];
    const float* emb     = (const float*)d_in[2];
    const float* Wqkv    = (const float*)d_in[3];
    const float* bqkv    = (const float*)d_in[4];
    const float* Wo      = (const float*)d_in[5];
    const float* bo      = (const float*)d_in[6];
    const float* W1      = (const float*)d_in[7];
    const float* b1      = (const float*)d_in[8];
    const float* W2      = (const float*)d_in[9];
    const float* b2      = (const float*)d_in[10];
    const float* ln1g    = (const float*)d_in[11];
    const float* ln1b    = (const float*)d_in[12];
    const float* ln2g    = (const float*)d_in[13];
    const float* ln2b    = (const float*)d_in[14];
    const float* We1     = (const float*)d_in[15];
    const float* be1     = (const float*)d_in[16];
    const float* We2     = (const float*)d_in[17];
    const float* be2     = (const float*)d_in[18];
    const float* dp_w1   = (const float*)d_in[19];
    const float* dp_b1   = (const float*)d_in[20];
    const float* dp_g1   = (const float*)d_in[21];
    const float* dp_bt1  = (const float*)d_in[22];
    const float* dp_m1   = (const float*)d_in[23];
    const float* dp_v1   = (const float*)d_in[24];
    const float* dp_w2   = (const float*)d_in[25];
    const float* dp_b2   = (const float*)d_in[26];
    const float* dp_g2   = (const float*)d_in[27];
    const float* dp_bt2  = (const float*)d_in[28];
    const float* dp_m2   = (const float*)d_in[29];
    const float* dp_v2   = (const float*)d_in[30];
    const float* dp_wo   = (const float*)d_in[31];
    const float* dp_bo   = (const float*)d_in[32];
    const float* dec_w3  = (const float*)d_in[37];
    const float* dec_b1  = (const float*)d_in[34];
    const float* dec_b2  = (const float*)d_in[36];
    const float* dec_b3  = (const float*)d_in[38];

    float* ws   = (float*)d_ws;
    float* x    = ws + OFF_X;
    unsigned short* ffhB = (unsigned short*)(ws + OFF_FFH);
    unsigned short* Wbt  = (unsigned short*)(ws + OFF_WBT);
    unsigned short* cw   = (unsigned short*)(ws + OFF_CWT);
    unsigned short* wtbdp1 = cw;
    unsigned short* wtbdp2 = cw + 196608;
    unsigned short* wtb1   = cw + 393216;
    unsigned short* wtb2   = cw + 720896;
    unsigned short* qkvB = (unsigned short*)(ws + OFF_QKV);
    unsigned short* vtb  = qkvB + 12582912;
    unsigned short* regB = qkvB;
    float* attb = ws + OFF_ATTN;
    float* prjb = ws + OFF_PROJ;
    unsigned short* attbB = (unsigned short*)attb;
    unsigned short* h1b  = (unsigned short*)attb;
    unsigned short* d1b  = ffhB;
    unsigned short* d2b  = (unsigned short*)attb;
    int*   ip     = (int*)(ws + OFF_INT);
    int*   durb   = ip;
    int*   tokb   = ip + 16384;

    const int M = NB * NT;   // 16384

    embed_kernel<<<M, 256, 0, stream>>>(text, emb, x);
    wqall_kernel<<<dim3(768, 6), 256, 0, stream>>>(Wqkv, Wo, W1, W2, Wbt);
    wtransball_kernel<<<3456, 256, 0, stream>>>(dp_w1, dp_w2,
                                                (const float*)d_in[33], (const float*)d_in[35], cw);

    for (int l = 0; l < NLAYER; ++l) {
        const unsigned short* WQ  = Wbt + (size_t)l * 786432;
        const unsigned short* WO  = WQ + 196608;
        const unsigned short* WF1 = WQ + 262144;
        const unsigned short* WF2 = WQ + 524288;
        gemmbf_kernel<128, false, false, true, true><<<dim3(6, 128), 256, 0, stream>>>(
            x, WQ, bqkv + l * 768, qkvB, vtb, M, 768, 256);
        attn3_kernel<<<dim3(NT / 128, NH, NB), 256, 0, stream>>>(qkvB, vtb, attbB);
        gemmln_kernel<<<M / 64, 256, 0, stream>>>(
            attbB, WO, bo + l * 256, ln1g + l * ND, ln1b + l * ND, x, 256);
        gemmbf_kernel<128, true, false, true, false><<<dim3(8, 128), 256, 0, stream>>>(
            x, WF1, b1 + l * 1024, ffhB, nullptr, M, 1024, 256);
        gemmln_kernel<<<M / 64, 256, 0, stream>>>(
            ffhB, WF2, b2 + l * 256, ln2g + l * ND, ln2b + l * ND, x, 1024);
    }

    fuse_kernel<<<M, 256, 0, stream>>>(emotion, We1, be1, We2, be2, x);

    convk_kernel<256, 3, false, true, true><<<dim3(2, 4, NB), 256, 0, stream>>>(
        x, wtbdp1, dp_b1, dp_g1, dp_bt1, dp_m1, dp_v1, h1b, NT, 256);
    convk_kernel<256, 3, true, false, true><<<dim3(2, 4, NB), 256, 0, stream>>>(
        h1b, wtbdp2, dp_b2, dp_g2, dp_bt2, dp_m2, dp_v2, prjb, NT, 256);
    dur_kernel<<<M / 4, 256, 0, stream>>>(prjb, dp_wo, dp_bo, durb);
    scantok_kernel<<<NB, 256, 0, stream>>>(durb, tokb);

    reg_kernel<<<NB * TOUT / 4, 256, 0, stream>>>(x, tokb, regB);
    convk_kernel<256, 5, true, true, false><<<dim3(TOUT / 256, 4, NB), 256, 0, stream>>>(
        regB, wtb1, dec_b1, nullptr, nullptr, nullptr, nullptr, d1b, TOUT, 256);
    convk_kernel<256, 5, true, true, false><<<dim3(TOUT / 256, 2, NB), 256, 0, stream>>>(
        d1b, wtb2, dec_b2, nullptr, nullptr, nullptr, nullptr, d2b, TOUT, 128);
    conv3_kernel<<<NB * TOUT / 4, 256, 0, stream>>>(d2b, dec_w3, dec_b3, (float*)d_out);
}